// Round 4
// baseline (462.204 us; speedup 1.0000x reference)
//
#include <hip/hip_runtime.h>
#include <hip/hip_bf16.h>
#include <cstdio>
#include <cstdint>

// Attention (B=4, S=2048, D=1024, full-dim, fp32 I/O) via bf16 MFMA GEMMs.
// Round 4: register-pipelined 8-window GEMM — each window reads NEXT
// quadrant's operands, counted lgkmcnt (never 0 in steady loop), one
// barrier/window, full-tile stage once per K-tile, vmcnt(0) only at
// 2-window distance. LDS reads overlap MFMA across windows.

typedef __attribute__((ext_vector_type(8))) short short8;
typedef __attribute__((ext_vector_type(4))) float f32x4;

#define AS1(p) ((const __attribute__((address_space(1))) void*)(p))
#define AS3(p) ((__attribute__((address_space(3))) void*)(p))

__device__ __forceinline__ unsigned short f2bf(float f) {
  union { float f; uint32_t u; } c; c.f = f;
  uint32_t u = c.u + 0x7fffu + ((c.u >> 16) & 1u);  // RNE (no NaN inputs here)
  return (unsigned short)(u >> 16);
}

// ---------------- fp32 -> bf16 convert (float4 -> ushort4) ----------------
__global__ void cvt_f32_bf16(const float* __restrict__ in,
                             unsigned short* __restrict__ out, int n4) {
  int i = blockIdx.x * 256 + threadIdx.x;
  if (i >= n4) return;
  float4 v = ((const float4*)in)[i];
  ushort4 o;
  o.x = f2bf(v.x); o.y = f2bf(v.y); o.z = f2bf(v.z); o.w = f2bf(v.w);
  ((ushort4*)out)[i] = o;
}

// all 4 weight matrices in one launch (each 1,048,576 elems, out contiguous)
__global__ void cvt_w4(const float* __restrict__ a, const float* __restrict__ b,
                       const float* __restrict__ c, const float* __restrict__ d,
                       unsigned short* __restrict__ out) {
  const float* s = (blockIdx.y == 0) ? a : (blockIdx.y == 1) ? b
                 : (blockIdx.y == 2) ? c : d;
  int i = blockIdx.x * 256 + threadIdx.x;
  float4 v = ((const float4*)s)[i];
  ushort4 o;
  o.x = f2bf(v.x); o.y = f2bf(v.y); o.z = f2bf(v.z); o.w = f2bf(v.w);
  ((ushort4*)(out + (size_t)blockIdx.y * 1048576))[i] = o;
}

// ---------------- bf16 [2048][1024] -> [1024][2048] transpose (per batch) --
__global__ void transpose_bf16(const unsigned short* __restrict__ V,
                               unsigned short* __restrict__ Vt) {
  __shared__ unsigned short tile[64][72];
  const int b = blockIdx.z;
  const unsigned short* v = V + (size_t)b * 2048 * 1024;
  unsigned short* vt = Vt + (size_t)b * 1024 * 2048;
  const int d0 = blockIdx.x * 64, s0 = blockIdx.y * 64;
  const int t = threadIdx.x;
#pragma unroll
  for (int it = 0; it < 16; ++it) {
    int idx = it * 256 + t, r = idx >> 6, c = idx & 63;
    tile[r][c] = v[(size_t)(s0 + r) * 1024 + d0 + c];
  }
  __syncthreads();
#pragma unroll
  for (int it = 0; it < 16; ++it) {
    int idx = it * 256 + t, r = idx >> 6, c = idx & 63;
    vt[(size_t)(d0 + r) * 2048 + s0 + c] = tile[c][r];
  }
}

// ---------------- row softmax: fp32 [rows][2048] -> bf16 P -----------------
__global__ void softmax_rows(const float* __restrict__ S,
                             unsigned short* __restrict__ P) {
  const size_t row = blockIdx.x;
  const float* s = S + row * 2048;
  const int t = threadIdx.x, l = t & 63, w = t >> 6;
  float4 v0 = ((const float4*)s)[t * 2];
  float4 v1 = ((const float4*)s)[t * 2 + 1];
  float x[8] = {v0.x, v0.y, v0.z, v0.w, v1.x, v1.y, v1.z, v1.w};
  float m = x[0];
#pragma unroll
  for (int j = 1; j < 8; ++j) m = fmaxf(m, x[j]);
#pragma unroll
  for (int d = 32; d; d >>= 1) m = fmaxf(m, __shfl_xor(m, d));
  __shared__ float rm[4], rs[4];
  if (l == 0) rm[w] = m;
  __syncthreads();
  m = fmaxf(fmaxf(rm[0], rm[1]), fmaxf(rm[2], rm[3]));
  float e[8], sum = 0.f;
#pragma unroll
  for (int j = 0; j < 8; ++j) { e[j] = __expf(x[j] - m); sum += e[j]; }
#pragma unroll
  for (int d = 32; d; d >>= 1) sum += __shfl_xor(sum, d);
  if (l == 0) rs[w] = sum;
  __syncthreads();
  float inv = 1.0f / (rs[0] + rs[1] + rs[2] + rs[3]);
  short8 o;
#pragma unroll
  for (int j = 0; j < 8; ++j) o[j] = (short)f2bf(e[j] * inv);
  *(short8*)(P + row * 2048 + t * 8) = o;
}

// ---------------- pipelined 8-window 256x256 GEMM, C = scale*A@B^T ---------
// LDS: 2 slots x 64KB (slot s at s*65536): A at +0 (h0 16KB, h1 16KB),
// B at +32768. Chunk (fr,kk) at (fr*2+kk)*1024 + l*16 (fragment-linear,
// conflict-free; stage permutation rides on the per-lane global address).
// 8 waves 2Mx4N, wave tile 128x64, quadrant order (A0b0)(A0b1)(A1b0)(A1b1).
// Window = {reads for NEXT quadrant | stage | lgkmcnt(counted) |
// sched_barrier | 16 MFMA | [vmcnt(0) at 2-window distance] | s_barrier}.
// Hazard ledger: slot-s reads drain at w3/w7 lgkm -> stage slot-s at w4/w8
// (>=1 barrier after); stage drains at w2/w6 vmcnt+barrier -> reads at w3/w7.
__device__ __forceinline__ void store_out(float* p, float v) { *p = v; }
__device__ __forceinline__ void store_out(unsigned short* p, float v) { *p = f2bf(v); }

template <typename OutT>
__global__ __launch_bounds__(512, 2) void gemm8w(
    const unsigned short* __restrict__ A, const unsigned short* __restrict__ B,
    OutT* __restrict__ C, int lda, int ldb, int ldc, int nT,  // nT = K/64, even
    long long aStride, long long bStride, long long cStride, float scale) {
  __shared__ unsigned short lds[65536];  // 128 KiB
  const int l = threadIdx.x & 63, w = threadIdx.x >> 6;
  const int wr = w >> 2, wc = w & 3;  // 2M x 4N waves

  // bijective XCD-aware block swizzle (all grids here have nwg % 8 == 0)
  const int gx = gridDim.x, gy = gridDim.y;
  int f = blockIdx.x + gx * (blockIdx.y + gy * blockIdx.z);
  int nwg = gx * gy * gridDim.z;
  int work = ((nwg & 7) == 0) ? ((f & 7) * (nwg >> 3) + (f >> 3)) : f;
  const int bx = work % gx;
  int rem = work / gx;
  const int by = rem % gy, bz = rem / gy;
  const long long r0 = (long long)by * 256, c0 = (long long)bx * 256;
  A += (size_t)bz * aStride;
  B += (size_t)bz * bStride;
  C += (size_t)bz * cStride;

  const unsigned short* aS = A + (size_t)(r0 + w * 16 + (l & 15)) * lda + (l >> 4) * 8;
  const unsigned short* bS = B + (size_t)(c0 + w * 16 + (l & 15)) * ldb + (l >> 4) * 8;
  const size_t a128 = (size_t)128 * lda, b128 = (size_t)128 * ldb;
  char* const ldsc = (char*)lds;
  const int dstW = (w * 2) << 10;
  const int aBase = wr << 14;
  const int bBase = 32768 + ((wc >> 1) << 14);
  const int bFr = (wc & 1) * 4;
  const int loff = l * 16;

// stage one FULL K-tile (A h0,h1 + B h0,h1; 8 loads/thread) into slot_
#define STG(slot_, koff_)                                                      \
  do {                                                                         \
    const unsigned short* sa_ = aS + (koff_);                                  \
    const unsigned short* sb_ = bS + (koff_);                                  \
    char* da_ = ldsc + ((slot_) << 16) + dstW;                                 \
    char* db_ = ldsc + ((slot_) << 16) + 32768 + dstW;                         \
    __builtin_amdgcn_global_load_lds(AS1(sa_), AS3(da_), 16, 0, 0);            \
    __builtin_amdgcn_global_load_lds(AS1(sa_ + 32), AS3(da_ + 1024), 16, 0, 0);\
    __builtin_amdgcn_global_load_lds(AS1(sa_ + a128), AS3(da_ + 16384), 16, 0, 0);\
    __builtin_amdgcn_global_load_lds(AS1(sa_ + a128 + 32), AS3(da_ + 17408), 16, 0, 0);\
    __builtin_amdgcn_global_load_lds(AS1(sb_), AS3(db_), 16, 0, 0);            \
    __builtin_amdgcn_global_load_lds(AS1(sb_ + 32), AS3(db_ + 1024), 16, 0, 0);\
    __builtin_amdgcn_global_load_lds(AS1(sb_ + b128), AS3(db_ + 16384), 16, 0, 0);\
    __builtin_amdgcn_global_load_lds(AS1(sb_ + b128 + 32), AS3(db_ + 17408), 16, 0, 0);\
  } while (0)

#define RDA(dst_, slot_, hs_)                                                  \
  _Pragma("unroll") for (int f2 = 0; f2 < 4; ++f2)                             \
  _Pragma("unroll") for (int kk = 0; kk < 2; ++kk)                             \
      dst_[f2 * 2 + kk] = *(const short8*)(ldsc + ((slot_) << 16) + aBase +    \
                                           ((((hs_) * 4 + f2) * 2 + kk) << 10) + loff);
#define RDB(dst_, slot_, qn_)                                                  \
  _Pragma("unroll") for (int n2 = 0; n2 < 2; ++n2)                             \
  _Pragma("unroll") for (int kk = 0; kk < 2; ++kk)                             \
      dst_[n2 * 2 + kk] = *(const short8*)(ldsc + ((slot_) << 16) + bBase +    \
                                           (((bFr + (qn_) * 2 + n2) * 2 + kk) << 10) + loff);
#define MQ(ar_, mo_, br_, no_)                                                 \
  __builtin_amdgcn_s_setprio(1);                                               \
  _Pragma("unroll") for (int m2 = 0; m2 < 4; ++m2)                             \
  _Pragma("unroll") for (int n2 = 0; n2 < 2; ++n2)                             \
  _Pragma("unroll") for (int kk = 0; kk < 2; ++kk)                             \
      acc[(mo_) + m2][(no_) + n2] = __builtin_amdgcn_mfma_f32_16x16x32_bf16(   \
          ar_[m2 * 2 + kk], br_[n2 * 2 + kk], acc[(mo_) + m2][(no_) + n2], 0, 0, 0); \
  __builtin_amdgcn_s_setprio(0);
#define BAR() asm volatile("s_barrier" ::: "memory")
#define LGKM(n_) asm volatile("s_waitcnt lgkmcnt(" #n_ ")" ::: "memory")
#define VMC(n_) asm volatile("s_waitcnt vmcnt(" #n_ ")" ::: "memory")
#define SB() __builtin_amdgcn_sched_barrier(0)

  short8 aE[8], aO[8], b0r[4], b1r[4];
  f32x4 acc[8][4] = {};

  // prologue: stage tiles 0,1; wait slot0; pre-read A0,b0
  STG(0, 0);
  STG(1, 64);
  VMC(8); BAR();
  RDA(aE, 0, 0);
  RDB(b0r, 0, 0);

  const int nI = nT >> 1;
  for (int i = 0; i < nI; ++i) {
    const bool last = (i == nI - 1);
    // ---- K-tile at slot 0 ----
    // w1: MFMA(A0,b0); read b1
    RDB(b1r, 0, 1); LGKM(4); SB();
    MQ(aE, 0, b0r, 0); BAR();
    // w2: MFMA(A0,b1); read A1; drain slot1 stage (2 windows old)
    RDA(aO, 0, 1); LGKM(8); SB();
    MQ(aE, 0, b1r, 2); VMC(0); BAR();
    // w3: MFMA(A1,b0); read A0' (slot1)
    RDA(aE, 1, 0); LGKM(8); SB();
    MQ(aO, 4, b0r, 0); BAR();
    // w4: MFMA(A1,b1); read b0' (slot1); stage tile t0+2 -> slot0
    RDB(b0r, 1, 0);
    if (!last) STG(0, 128);
    MQ(aO, 4, b1r, 2); BAR();
    // ---- K-tile at slot 1 ----
    // w5: MFMA(A0',b0'); read b1'
    RDB(b1r, 1, 1); LGKM(4); SB();
    MQ(aE, 0, b0r, 0); BAR();
    // w6: MFMA(A0',b1'); read A1'; drain slot0 stage
    RDA(aO, 1, 1); LGKM(8); SB();
    MQ(aE, 0, b1r, 2); VMC(0); BAR();
    // w7: MFMA(A1',b0'); read A0'' (slot0, tile t0+2)
    if (!last) { RDA(aE, 0, 0); LGKM(8); } else { LGKM(0); }
    SB();
    MQ(aO, 4, b0r, 0); BAR();
    // w8: MFMA(A1',b1'); read b0'' (slot0); stage tile t0+3 -> slot1
    if (!last) { RDB(b0r, 0, 0); STG(1, 192); }
    MQ(aO, 4, b1r, 2); BAR();
    aS += 128; bS += 128;
  }
#undef STG
#undef RDA
#undef RDB
#undef MQ

  // C-write. C/D layout (round-1 verified): col = lane&15, row = (lane>>4)*4+i
  const int cr = (l >> 4) * 4, cc = l & 15;
  const long long rowb = r0 + wr * 128, colb = c0 + wc * 64;
#pragma unroll
  for (int m = 0; m < 8; ++m)
#pragma unroll
    for (int n = 0; n < 4; ++n) {
      long long col = colb + n * 16 + cc;
#pragma unroll
      for (int i2 = 0; i2 < 4; ++i2) {
        long long row = rowb + m * 16 + cr + i2;
        store_out(&C[row * ldc + col], acc[m][n][i2] * scale);
      }
    }
}

// ---------------- workspace layout (bytes, all 256-aligned) ----------------
static const size_t OFF_XB  = 0;            // x bf16        16,777,216
static const size_t OFF_WQ  = 16777216;     // wq bf16        2,097,152
static const size_t OFF_WK  = 18874368;
static const size_t OFF_WV  = 20971520;
static const size_t OFF_WO  = 23068672;
static const size_t OFF_Q   = 25165824;     // Q bf16        16,777,216
static const size_t OFF_K   = 41943040;
static const size_t OFF_V   = 58720256;
static const size_t OFF_VT  = 75497472;     // V^T bf16      16,777,216
static const size_t OFF_SC  = 92274688;     // scores fp32   67,108,864
static const size_t OFF_P   = 159383552;    // P bf16        33,554,432
static const size_t OFF_CTX = 192937984;    // ctx bf16      16,777,216
static const size_t WS_NEED = 209715200;    // 200 MiB

extern "C" void kernel_launch(void* const* d_in, const int* in_sizes, int n_in,
                              void* d_out, int out_size, void* d_ws, size_t ws_size,
                              hipStream_t stream) {
  const float* x  = (const float*)d_in[0];
  const float* wq = (const float*)d_in[1];
  const float* wk = (const float*)d_in[2];
  const float* wv = (const float*)d_in[3];
  const float* wo = (const float*)d_in[4];
  float* out = (float*)d_out;

  if (ws_size < WS_NEED) {
    fprintf(stderr, "kernel_launch: ws_size=%zu < needed %zu\n", ws_size, WS_NEED);
    return;
  }
  char* ws = (char*)d_ws;
  unsigned short* xb  = (unsigned short*)(ws + OFF_XB);
  unsigned short* wqb = (unsigned short*)(ws + OFF_WQ);
  unsigned short* wob = (unsigned short*)(ws + OFF_WO);
  unsigned short* Qb  = (unsigned short*)(ws + OFF_Q);
  unsigned short* Kb  = (unsigned short*)(ws + OFF_K);
  unsigned short* Vb  = (unsigned short*)(ws + OFF_V);
  unsigned short* Vt  = (unsigned short*)(ws + OFF_VT);
  float*          Sc  = (float*)(ws + OFF_SC);
  unsigned short* Pb  = (unsigned short*)(ws + OFF_P);
  unsigned short* Cx  = (unsigned short*)(ws + OFF_CTX);

  // 1) convert inputs to bf16 (weights land contiguous at OFF_WQ..OFF_WO)
  cvt_f32_bf16<<<8192, 256, 0, stream>>>(x, xb, 2097152);
  cvt_w4<<<dim3(1024, 4, 1), 256, 0, stream>>>(wq, wk, wv, wo, wqb);

  // 2) fused QKV: z selects weight (bStride) and output (cStride)
  gemm8w<unsigned short><<<dim3(4, 32, 3), 512, 0, stream>>>(
      xb, wqb, Qb, 1024, 1024, 1024, 16, 0, 1048576LL, 8388608LL, 1.0f);

  // 3) V^T per batch
  transpose_bf16<<<dim3(16, 32, 4), 256, 0, stream>>>(Vb, Vt);

  // 4) scores = Q @ K^T / 32  (per batch, M=N=2048, K=1024, fp32 out)
  gemm8w<float><<<dim3(8, 8, 4), 512, 0, stream>>>(
      Qb, Kb, Sc, 1024, 1024, 2048, 16,
      2097152LL, 2097152LL, 4194304LL, 0.03125f);

  // 5) P = softmax(scores) -> bf16
  softmax_rows<<<8192, 256, 0, stream>>>(Sc, Pb);

  // 6) ctx = P @ V  (per batch, M=2048, N=1024, K=2048)
  gemm8w<unsigned short><<<dim3(4, 8, 4), 512, 0, stream>>>(
      Pb, Vt, Cx, 2048, 2048, 1024, 32,
      4194304LL, 2097152LL, 2097152LL, 1.0f);

  // 7) out = ctx @ wo^T  (M=8192, N=1024, K=1024)
  gemm8w<float><<<dim3(4, 32, 1), 512, 0, stream>>>(
      Cx, wob, out, 1024, 1024, 1024, 16, 0, 0, 0, 1.0f);
}

// Round 5
// 376.739 us; speedup vs baseline: 1.2269x; 1.2269x over previous
//
#include <hip/hip_runtime.h>
#include <hip/hip_bf16.h>
#include <cstdio>
#include <cstdint>

// Attention (B=4, S=2048, D=1024, full-dim, fp32 I/O) via bf16 MFMA GEMMs.
// Round 5: 128x128 tile, BK=64, 4 waves, 64 KB LDS -> 2 blocks/CU (two
// independent barrier domains). Register-double-buffered K-loop: per K-tile
// {stage t+2 | MFMA half1 | vmcnt(8) | bar | ds_read t+1 ∥ MFMA half2 |
// lgkm(0) | bar}. Counted vmcnt (0 only at tail), 2 barriers/K-tile.

typedef __attribute__((ext_vector_type(8))) short short8;
typedef __attribute__((ext_vector_type(4))) float f32x4;

#define AS1(p) ((const __attribute__((address_space(1))) void*)(p))
#define AS3(p) ((__attribute__((address_space(3))) void*)(p))

__device__ __forceinline__ unsigned short f2bf(float f) {
  union { float f; uint32_t u; } c; c.f = f;
  uint32_t u = c.u + 0x7fffu + ((c.u >> 16) & 1u);  // RNE (no NaN inputs here)
  return (unsigned short)(u >> 16);
}

// ---------------- fp32 -> bf16 convert (float4 -> ushort4) ----------------
__global__ void cvt_f32_bf16(const float* __restrict__ in,
                             unsigned short* __restrict__ out, int n4) {
  int i = blockIdx.x * 256 + threadIdx.x;
  if (i >= n4) return;
  float4 v = ((const float4*)in)[i];
  ushort4 o;
  o.x = f2bf(v.x); o.y = f2bf(v.y); o.z = f2bf(v.z); o.w = f2bf(v.w);
  ((ushort4*)out)[i] = o;
}

// all 4 weight matrices in one launch (each 1,048,576 elems, out contiguous)
__global__ void cvt_w4(const float* __restrict__ a, const float* __restrict__ b,
                       const float* __restrict__ c, const float* __restrict__ d,
                       unsigned short* __restrict__ out) {
  const float* s = (blockIdx.y == 0) ? a : (blockIdx.y == 1) ? b
                 : (blockIdx.y == 2) ? c : d;
  int i = blockIdx.x * 256 + threadIdx.x;
  float4 v = ((const float4*)s)[i];
  ushort4 o;
  o.x = f2bf(v.x); o.y = f2bf(v.y); o.z = f2bf(v.z); o.w = f2bf(v.w);
  ((ushort4*)(out + (size_t)blockIdx.y * 1048576))[i] = o;
}

// ---------------- bf16 [2048][1024] -> [1024][2048] transpose (per batch) --
__global__ void transpose_bf16(const unsigned short* __restrict__ V,
                               unsigned short* __restrict__ Vt) {
  __shared__ unsigned short tile[64][72];
  const int b = blockIdx.z;
  const unsigned short* v = V + (size_t)b * 2048 * 1024;
  unsigned short* vt = Vt + (size_t)b * 1024 * 2048;
  const int d0 = blockIdx.x * 64, s0 = blockIdx.y * 64;
  const int t = threadIdx.x;
#pragma unroll
  for (int it = 0; it < 16; ++it) {
    int idx = it * 256 + t, r = idx >> 6, c = idx & 63;
    tile[r][c] = v[(size_t)(s0 + r) * 1024 + d0 + c];
  }
  __syncthreads();
#pragma unroll
  for (int it = 0; it < 16; ++it) {
    int idx = it * 256 + t, r = idx >> 6, c = idx & 63;
    vt[(size_t)(d0 + r) * 2048 + s0 + c] = tile[c][r];
  }
}

// ---------------- row softmax: fp32 [rows][2048] -> bf16 P -----------------
__global__ void softmax_rows(const float* __restrict__ S,
                             unsigned short* __restrict__ P) {
  const size_t row = blockIdx.x;
  const float* s = S + row * 2048;
  const int t = threadIdx.x, l = t & 63, w = t >> 6;
  float4 v0 = ((const float4*)s)[t * 2];
  float4 v1 = ((const float4*)s)[t * 2 + 1];
  float x[8] = {v0.x, v0.y, v0.z, v0.w, v1.x, v1.y, v1.z, v1.w};
  float m = x[0];
#pragma unroll
  for (int j = 1; j < 8; ++j) m = fmaxf(m, x[j]);
#pragma unroll
  for (int d = 32; d; d >>= 1) m = fmaxf(m, __shfl_xor(m, d));
  __shared__ float rm[4], rs[4];
  if (l == 0) rm[w] = m;
  __syncthreads();
  m = fmaxf(fmaxf(rm[0], rm[1]), fmaxf(rm[2], rm[3]));
  float e[8], sum = 0.f;
#pragma unroll
  for (int j = 0; j < 8; ++j) { e[j] = __expf(x[j] - m); sum += e[j]; }
#pragma unroll
  for (int d = 32; d; d >>= 1) sum += __shfl_xor(sum, d);
  if (l == 0) rs[w] = sum;
  __syncthreads();
  float inv = 1.0f / (rs[0] + rs[1] + rs[2] + rs[3]);
  short8 o;
#pragma unroll
  for (int j = 0; j < 8; ++j) o[j] = (short)f2bf(e[j] * inv);
  *(short8*)(P + row * 2048 + t * 8) = o;
}

// ---------------- pipelined 128x128 GEMM, C = scale * A @ B^T --------------
// LDS: 2 slots x 32KB (slot s at s*32768): A chunks at +0..16K, B at +16K.
// Chunk (fr,kk), fr=row-frag 0..7, kk=K-half 0..1, at (fr*2+kk)*1024 + l*16;
// lane l holds M[fr*16+(l&15)][t*64 + kk*32 + (l>>4)*8 ..+8] (fragment-
// linear, conflict-free; stage permutation rides on the global src addr).
// 4 waves 2Mx2N (wave tile 64x64). Per-thread stage = 8 x 16B (full A+B).
// Hazards: stage into slot s is >=1 barrier after slot-s reads drained
// (lgkm(0)+bar at each step end); reads follow vmcnt(8)+bar certifying all
// waves' stage of that slot completed. vmcnt hits 0 only in the tail.
__device__ __forceinline__ void store_out(float* p, float v) { *p = v; }
__device__ __forceinline__ void store_out(unsigned short* p, float v) { *p = f2bf(v); }

template <typename OutT>
__global__ __launch_bounds__(256, 2) void gemmP(
    const unsigned short* __restrict__ A, const unsigned short* __restrict__ B,
    OutT* __restrict__ C, int lda, int ldb, int ldc, int nT,  // nT = K/64, even
    long long aStride, long long bStride, long long cStride, float scale) {
  __shared__ unsigned short lds[32768];  // 64 KB -> 2 blocks/CU
  const int l = threadIdx.x & 63, w = threadIdx.x >> 6;
  const int wr = w >> 1, wc = w & 1;

  // bijective XCD-aware block swizzle (all grids here have nwg % 8 == 0)
  const int gx = gridDim.x, gy = gridDim.y;
  int f = blockIdx.x + gx * (blockIdx.y + gy * blockIdx.z);
  int nwg = gx * gy * gridDim.z;
  int work = ((nwg & 7) == 0) ? ((f & 7) * (nwg >> 3) + (f >> 3)) : f;
  const int bx = work % gx;
  int rem = work / gx;
  const int by = rem % gy, bz = rem / gy;
  const long long r0 = (long long)by * 128, c0 = (long long)bx * 128;
  A += (size_t)bz * aStride;
  B += (size_t)bz * bStride;
  C += (size_t)bz * cStride;

  // stage sources: wave w owns row-frags {2w, 2w+1} of both A and B
  const unsigned short* aS = A + (size_t)(r0 + 2 * w * 16 + (l & 15)) * lda + (l >> 4) * 8;
  const unsigned short* bS = B + (size_t)(c0 + 2 * w * 16 + (l & 15)) * ldb + (l >> 4) * 8;
  const size_t a16 = (size_t)16 * lda, b16 = (size_t)16 * ldb;
  char* const ldsc = (char*)lds;
  const int dstW = w * 4096;

#define GLD(s_, d_) __builtin_amdgcn_global_load_lds(AS1(s_), AS3(d_), 16, 0, 0)
#define STG(slot_, t_)                                                         \
  do {                                                                         \
    const unsigned short* sa_ = aS + (size_t)(t_) * 64;                        \
    const unsigned short* sb_ = bS + (size_t)(t_) * 64;                        \
    char* da_ = ldsc + ((slot_) << 15) + dstW;                                 \
    char* db_ = da_ + 16384;                                                   \
    GLD(sa_, da_); GLD(sa_ + 32, da_ + 1024);                                  \
    GLD(sa_ + a16, da_ + 2048); GLD(sa_ + a16 + 32, da_ + 3072);               \
    GLD(sb_, db_); GLD(sb_ + 32, db_ + 1024);                                  \
    GLD(sb_ + b16, db_ + 2048); GLD(sb_ + b16 + 32, db_ + 3072);               \
  } while (0)

#define RDAB(aD_, bD_, slot_)                                                  \
  do {                                                                         \
    _Pragma("unroll") for (int m = 0; m < 4; ++m)                              \
    _Pragma("unroll") for (int kk = 0; kk < 2; ++kk)                           \
        aD_[m * 2 + kk] = *(const short8*)(ldsc + ((slot_) << 15) +            \
                              (((wr * 4 + m) * 2 + kk) << 10) + l * 16);       \
    _Pragma("unroll") for (int n = 0; n < 4; ++n)                              \
    _Pragma("unroll") for (int kk = 0; kk < 2; ++kk)                           \
        bD_[n * 2 + kk] = *(const short8*)(ldsc + ((slot_) << 15) + 16384 +    \
                              (((wc * 4 + n) * 2 + kk) << 10) + l * 16);       \
  } while (0)

#define MH(aR_, bR_, n0_)                                                      \
  __builtin_amdgcn_s_setprio(1);                                               \
  _Pragma("unroll") for (int m = 0; m < 4; ++m)                                \
  _Pragma("unroll") for (int n = 0; n < 2; ++n)                                \
  _Pragma("unroll") for (int kk = 0; kk < 2; ++kk)                             \
      acc[m][(n0_) + n] = __builtin_amdgcn_mfma_f32_16x16x32_bf16(             \
          aR_[m * 2 + kk], bR_[((n0_) + n) * 2 + kk], acc[m][(n0_) + n], 0, 0, 0); \
  __builtin_amdgcn_s_setprio(0);
#define BAR() asm volatile("s_barrier" ::: "memory")
#define LGKM0() asm volatile("s_waitcnt lgkmcnt(0)" ::: "memory")
#define VMC(n_) asm volatile("s_waitcnt vmcnt(" #n_ ")" ::: "memory")
#define SB() __builtin_amdgcn_sched_barrier(0)

  short8 aE[8], bE[8], aO[8], bO[8];
  f32x4 acc[4][4] = {};

  // prologue: stage tiles 0,1; read tile 0
  STG(0, 0); STG(1, 1);
  VMC(8); BAR();
  RDAB(aE, bE, 0);
  LGKM0(); SB(); BAR();

  for (int t = 0; t < nT; t += 2) {
    // ---- even tile t (slot 0, regs E) ----
    if (t + 2 < nT) { STG(0, t + 2); }
    MH(aE, bE, 0);
    if (t + 2 < nT) { VMC(8); } else { VMC(0); }   // stage(t+1) resident
    BAR();
    RDAB(aO, bO, 1);                               // tile t+1 from slot 1
    MH(aE, bE, 2);                                 // overlaps the reads
    LGKM0(); SB(); BAR();
    // ---- odd tile t+1 (slot 1, regs O) ----
    if (t + 3 < nT) { STG(1, t + 3); }
    MH(aO, bO, 0);
    if (t + 3 < nT) { VMC(8); BAR(); RDAB(aE, bE, 0); }
    else if (t + 2 < nT) { VMC(0); BAR(); RDAB(aE, bE, 0); }
    MH(aO, bO, 2);
    LGKM0(); SB(); BAR();
  }
#undef GLD
#undef STG
#undef RDAB
#undef MH

  // C-write. C/D layout (round-1 verified): col = lane&15, row = (lane>>4)*4+i
  const int cr = (l >> 4) * 4, cc = l & 15;
  const long long rowb = r0 + wr * 64, colb = c0 + wc * 64;
#pragma unroll
  for (int m = 0; m < 4; ++m)
#pragma unroll
    for (int n = 0; n < 4; ++n) {
      long long col = colb + n * 16 + cc;
#pragma unroll
      for (int i2 = 0; i2 < 4; ++i2) {
        long long row = rowb + m * 16 + cr + i2;
        store_out(&C[row * ldc + col], acc[m][n][i2] * scale);
      }
    }
}

// ---------------- workspace layout (bytes, all 256-aligned) ----------------
static const size_t OFF_XB  = 0;            // x bf16        16,777,216
static const size_t OFF_WQ  = 16777216;     // wq bf16        2,097,152
static const size_t OFF_WK  = 18874368;
static const size_t OFF_WV  = 20971520;
static const size_t OFF_WO  = 23068672;
static const size_t OFF_Q   = 25165824;     // Q bf16        16,777,216
static const size_t OFF_K   = 41943040;
static const size_t OFF_V   = 58720256;
static const size_t OFF_VT  = 75497472;     // V^T bf16      16,777,216
static const size_t OFF_SC  = 92274688;     // scores fp32   67,108,864
static const size_t OFF_P   = 159383552;    // P bf16        33,554,432
static const size_t OFF_CTX = 192937984;    // ctx bf16      16,777,216
static const size_t WS_NEED = 209715200;    // 200 MiB

extern "C" void kernel_launch(void* const* d_in, const int* in_sizes, int n_in,
                              void* d_out, int out_size, void* d_ws, size_t ws_size,
                              hipStream_t stream) {
  const float* x  = (const float*)d_in[0];
  const float* wq = (const float*)d_in[1];
  const float* wk = (const float*)d_in[2];
  const float* wv = (const float*)d_in[3];
  const float* wo = (const float*)d_in[4];
  float* out = (float*)d_out;

  if (ws_size < WS_NEED) {
    fprintf(stderr, "kernel_launch: ws_size=%zu < needed %zu\n", ws_size, WS_NEED);
    return;
  }
  char* ws = (char*)d_ws;
  unsigned short* xb  = (unsigned short*)(ws + OFF_XB);
  unsigned short* wqb = (unsigned short*)(ws + OFF_WQ);
  unsigned short* wob = (unsigned short*)(ws + OFF_WO);
  unsigned short* Qb  = (unsigned short*)(ws + OFF_Q);
  unsigned short* Kb  = (unsigned short*)(ws + OFF_K);
  unsigned short* Vb  = (unsigned short*)(ws + OFF_V);
  unsigned short* Vt  = (unsigned short*)(ws + OFF_VT);
  float*          Sc  = (float*)(ws + OFF_SC);
  unsigned short* Pb  = (unsigned short*)(ws + OFF_P);
  unsigned short* Cx  = (unsigned short*)(ws + OFF_CTX);

  // 1) convert inputs to bf16 (weights land contiguous at OFF_WQ..OFF_WO)
  cvt_f32_bf16<<<8192, 256, 0, stream>>>(x, xb, 2097152);
  cvt_w4<<<dim3(1024, 4, 1), 256, 0, stream>>>(wq, wk, wv, wo, wqb);

  // 2) fused QKV: z selects weight (bStride) and output (cStride); 1536 blocks
  gemmP<unsigned short><<<dim3(8, 64, 3), 256, 0, stream>>>(
      xb, wqb, Qb, 1024, 1024, 1024, 16, 0, 1048576LL, 8388608LL, 1.0f);

  // 3) V^T per batch
  transpose_bf16<<<dim3(16, 32, 4), 256, 0, stream>>>(Vb, Vt);

  // 4) scores = Q @ K^T / 32  (per batch, M=N=2048, K=1024); 1024 blocks
  gemmP<float><<<dim3(16, 16, 4), 256, 0, stream>>>(
      Qb, Kb, Sc, 1024, 1024, 2048, 16,
      2097152LL, 2097152LL, 4194304LL, 0.03125f);

  // 5) P = softmax(scores) -> bf16
  softmax_rows<<<8192, 256, 0, stream>>>(Sc, Pb);

  // 6) ctx = P @ V  (per batch, M=2048, N=1024, K=2048); 512 blocks
  gemmP<unsigned short><<<dim3(8, 16, 4), 256, 0, stream>>>(
      Pb, Vt, Cx, 2048, 2048, 1024, 32,
      4194304LL, 2097152LL, 2097152LL, 1.0f);

  // 7) out = ctx @ wo^T  (M=8192, N=1024, K=1024); 512 blocks
  gemmP<float><<<dim3(8, 64, 1), 256, 0, stream>>>(
      Cx, wob, out, 1024, 1024, 1024, 16, 0, 0, 0, 1.0f);
}

// Round 6
// 355.770 us; speedup vs baseline: 1.2992x; 1.0589x over previous
//
#include <hip/hip_runtime.h>
#include <hip/hip_bf16.h>
#include <cstdio>
#include <cstdint>

// Attention (B=4, S=2048, D=1024, full-dim, fp32 I/O) via bf16 MFMA GEMMs.
// Round 6: work elimination around the proven gemmP core (510 TF, 2-phase
// ceiling at these shapes): V^T computed as GEMM (no transpose kernel),
// softmax folded into GEMM epilogues (scores writes bf16 exp(S/32); PV
// scales by 1/rowsum) + tiny rowsum kernel. One fused cvt launch.

typedef __attribute__((ext_vector_type(8))) short short8;
typedef __attribute__((ext_vector_type(4))) float f32x4;

#define AS1(p) ((const __attribute__((address_space(1))) void*)(p))
#define AS3(p) ((__attribute__((address_space(3))) void*)(p))

__device__ __forceinline__ unsigned short f2bf(float f) {
  union { float f; uint32_t u; } c; c.f = f;
  uint32_t u = c.u + 0x7fffu + ((c.u >> 16) & 1u);  // RNE (no NaN inputs here)
  return (unsigned short)(u >> 16);
}
__device__ __forceinline__ float bf2f(unsigned short h) {
  union { uint32_t u; float f; } c; c.u = ((uint32_t)h) << 16;
  return c.f;
}

// ---------------- fused fp32 -> bf16 convert: x + 4 weights ----------------
// blocks [0,8192): x (2M float4). blocks [8192,12288): weights, 1024 blocks
// each, outputs contiguous at wb + wi*1048576.
__global__ void cvt_all(const float* __restrict__ x, const float* __restrict__ wq,
                        const float* __restrict__ wk, const float* __restrict__ wv,
                        const float* __restrict__ wo, unsigned short* __restrict__ xb,
                        unsigned short* __restrict__ wb) {
  const int b = blockIdx.x;
  const float* src;
  unsigned short* dst;
  int idx;
  if (b < 8192) {
    src = x; dst = xb; idx = b * 256 + threadIdx.x;
  } else {
    int r = b - 8192, wi = r >> 10;
    src = (wi == 0) ? wq : (wi == 1) ? wk : (wi == 2) ? wv : wo;
    dst = wb + (size_t)wi * 1048576;
    idx = (r & 1023) * 256 + threadIdx.x;
  }
  float4 v = ((const float4*)src)[idx];
  ushort4 o;
  o.x = f2bf(v.x); o.y = f2bf(v.y); o.z = f2bf(v.z); o.w = f2bf(v.w);
  ((ushort4*)dst)[idx] = o;
}

// ---------------- rowsum of bf16 expS -> 1/sum (f32) -----------------------
// wave per row (4 rows / 256-thread block), no LDS, no block barrier.
__global__ void rowsum_inv(const unsigned short* __restrict__ P,
                           float* __restrict__ rsInv) {
  const int w = threadIdx.x >> 6, l = threadIdx.x & 63;
  const size_t row = (size_t)blockIdx.x * 4 + w;
  const unsigned short* p = P + row * 2048 + l * 32;
  float s = 0.f;
#pragma unroll
  for (int j = 0; j < 4; ++j) {
    short8 v = *(const short8*)(p + j * 8);
#pragma unroll
    for (int k = 0; k < 8; ++k) s += bf2f((unsigned short)v[k]);
  }
#pragma unroll
  for (int d = 32; d; d >>= 1) s += __shfl_xor(s, d);
  if (l == 0) rsInv[row] = 1.0f / s;
}

// ---------------- pipelined 128x128 GEMM, C = f(scale * A @ B^T) -----------
// (unchanged round-5 core: 2 slots x 32KB LDS -> 2 blocks/CU, reg-dbuf
// K-loop, counted vmcnt, fragment-linear LDS, conflicts=0.)
// MODE 0: C = scale*acc. MODE 1: C = bf16(exp(scale*acc)). MODE 2:
// C = scale*acc*rsInv[row] (softmax normalization moved past PV).
__device__ __forceinline__ void store_out(float* p, float v) { *p = v; }
__device__ __forceinline__ void store_out(unsigned short* p, float v) { *p = f2bf(v); }

template <typename OutT, int MODE>
__global__ __launch_bounds__(256, 2) void gemmP(
    const unsigned short* __restrict__ A, const unsigned short* __restrict__ B,
    OutT* __restrict__ C, int lda, int ldb, int ldc, int nT,  // nT = K/64, even
    long long aStride, long long bStride, long long cStride, float scale,
    const float* __restrict__ rsInv, long long rsStride) {
  __shared__ unsigned short lds[32768];  // 64 KB -> 2 blocks/CU
  const int l = threadIdx.x & 63, w = threadIdx.x >> 6;
  const int wr = w >> 1, wc = w & 1;

  // bijective XCD-aware block swizzle (all grids here have nwg % 8 == 0)
  const int gx = gridDim.x, gy = gridDim.y;
  int f = blockIdx.x + gx * (blockIdx.y + gy * blockIdx.z);
  int nwg = gx * gy * gridDim.z;
  int work = ((nwg & 7) == 0) ? ((f & 7) * (nwg >> 3) + (f >> 3)) : f;
  const int bx = work % gx;
  int rem = work / gx;
  const int by = rem % gy, bz = rem / gy;
  const long long r0 = (long long)by * 128, c0 = (long long)bx * 128;
  A += (size_t)bz * aStride;
  B += (size_t)bz * bStride;
  C += (size_t)bz * cStride;

  // stage sources: wave w owns row-frags {2w, 2w+1} of both A and B
  const unsigned short* aS = A + (size_t)(r0 + 2 * w * 16 + (l & 15)) * lda + (l >> 4) * 8;
  const unsigned short* bS = B + (size_t)(c0 + 2 * w * 16 + (l & 15)) * ldb + (l >> 4) * 8;
  const size_t a16 = (size_t)16 * lda, b16 = (size_t)16 * ldb;
  char* const ldsc = (char*)lds;
  const int dstW = w * 4096;

#define GLD(s_, d_) __builtin_amdgcn_global_load_lds(AS1(s_), AS3(d_), 16, 0, 0)
#define STG(slot_, t_)                                                         \
  do {                                                                         \
    const unsigned short* sa_ = aS + (size_t)(t_) * 64;                        \
    const unsigned short* sb_ = bS + (size_t)(t_) * 64;                        \
    char* da_ = ldsc + ((slot_) << 15) + dstW;                                 \
    char* db_ = da_ + 16384;                                                   \
    GLD(sa_, da_); GLD(sa_ + 32, da_ + 1024);                                  \
    GLD(sa_ + a16, da_ + 2048); GLD(sa_ + a16 + 32, da_ + 3072);               \
    GLD(sb_, db_); GLD(sb_ + 32, db_ + 1024);                                  \
    GLD(sb_ + b16, db_ + 2048); GLD(sb_ + b16 + 32, db_ + 3072);               \
  } while (0)

#define RDAB(aD_, bD_, slot_)                                                  \
  do {                                                                         \
    _Pragma("unroll") for (int m = 0; m < 4; ++m)                              \
    _Pragma("unroll") for (int kk = 0; kk < 2; ++kk)                           \
        aD_[m * 2 + kk] = *(const short8*)(ldsc + ((slot_) << 15) +            \
                              (((wr * 4 + m) * 2 + kk) << 10) + l * 16);       \
    _Pragma("unroll") for (int n = 0; n < 4; ++n)                              \
    _Pragma("unroll") for (int kk = 0; kk < 2; ++kk)                           \
        bD_[n * 2 + kk] = *(const short8*)(ldsc + ((slot_) << 15) + 16384 +    \
                              (((wc * 4 + n) * 2 + kk) << 10) + l * 16);       \
  } while (0)

#define MH(aR_, bR_, n0_)                                                      \
  __builtin_amdgcn_s_setprio(1);                                               \
  _Pragma("unroll") for (int m = 0; m < 4; ++m)                                \
  _Pragma("unroll") for (int n = 0; n < 2; ++n)                                \
  _Pragma("unroll") for (int kk = 0; kk < 2; ++kk)                             \
      acc[m][(n0_) + n] = __builtin_amdgcn_mfma_f32_16x16x32_bf16(             \
          aR_[m * 2 + kk], bR_[((n0_) + n) * 2 + kk], acc[m][(n0_) + n], 0, 0, 0); \
  __builtin_amdgcn_s_setprio(0);
#define BAR() asm volatile("s_barrier" ::: "memory")
#define LGKM0() asm volatile("s_waitcnt lgkmcnt(0)" ::: "memory")
#define VMC(n_) asm volatile("s_waitcnt vmcnt(" #n_ ")" ::: "memory")
#define SB() __builtin_amdgcn_sched_barrier(0)

  short8 aE[8], bE[8], aO[8], bO[8];
  f32x4 acc[4][4] = {};

  // prologue: stage tiles 0,1; read tile 0
  STG(0, 0); STG(1, 1);
  VMC(8); BAR();
  RDAB(aE, bE, 0);
  LGKM0(); SB(); BAR();

  for (int t = 0; t < nT; t += 2) {
    // ---- even tile t (slot 0, regs E) ----
    if (t + 2 < nT) { STG(0, t + 2); }
    MH(aE, bE, 0);
    if (t + 2 < nT) { VMC(8); } else { VMC(0); }   // stage(t+1) resident
    BAR();
    RDAB(aO, bO, 1);                               // tile t+1 from slot 1
    MH(aE, bE, 2);                                 // overlaps the reads
    LGKM0(); SB(); BAR();
    // ---- odd tile t+1 (slot 1, regs O) ----
    if (t + 3 < nT) { STG(1, t + 3); }
    MH(aO, bO, 0);
    if (t + 3 < nT) { VMC(8); BAR(); RDAB(aE, bE, 0); }
    else if (t + 2 < nT) { VMC(0); BAR(); RDAB(aE, bE, 0); }
    MH(aO, bO, 2);
    LGKM0(); SB(); BAR();
  }
#undef GLD
#undef STG
#undef RDAB
#undef MH

  // C-write. C/D layout (round-1 verified): col = lane&15, row = (lane>>4)*4+i
  const float* rs = (MODE == 2) ? (rsInv + (size_t)bz * rsStride) : nullptr;
  const int cr = (l >> 4) * 4, cc = l & 15;
  const long long rowb = r0 + wr * 64, colb = c0 + wc * 64;
#pragma unroll
  for (int m = 0; m < 4; ++m)
#pragma unroll
    for (int n = 0; n < 4; ++n) {
      long long col = colb + n * 16 + cc;
#pragma unroll
      for (int i2 = 0; i2 < 4; ++i2) {
        long long row = rowb + m * 16 + cr + i2;
        float v = acc[m][n][i2] * scale;
        if constexpr (MODE == 1) {
          store_out(&C[row * ldc + col], __expf(v));
        } else if constexpr (MODE == 2) {
          store_out(&C[row * ldc + col], v * rs[row]);
        } else {
          store_out(&C[row * ldc + col], v);
        }
      }
    }
}

// ---------------- workspace layout (bytes, all 256-aligned) ----------------
static const size_t OFF_XB  = 0;            // x bf16        16,777,216
static const size_t OFF_WQ  = 16777216;     // weights bf16   4 x 2,097,152
static const size_t OFF_WO  = 23068672;
static const size_t OFF_Q   = 25165824;     // Q bf16        16,777,216
static const size_t OFF_K   = 41943040;     // K bf16        16,777,216
static const size_t OFF_VT  = 75497472;     // V^T bf16 [1024][8192]
static const size_t OFF_RS  = 92274688;     // rowsumInv f32     32,768
static const size_t OFF_P   = 159383552;    // expS bf16     33,554,432
static const size_t OFF_CTX = 192937984;    // ctx bf16      16,777,216
static const size_t WS_NEED = 209715200;    // 200 MiB

extern "C" void kernel_launch(void* const* d_in, const int* in_sizes, int n_in,
                              void* d_out, int out_size, void* d_ws, size_t ws_size,
                              hipStream_t stream) {
  const float* x  = (const float*)d_in[0];
  const float* wq = (const float*)d_in[1];
  const float* wk = (const float*)d_in[2];
  const float* wv = (const float*)d_in[3];
  const float* wo = (const float*)d_in[4];
  float* out = (float*)d_out;

  if (ws_size < WS_NEED) {
    fprintf(stderr, "kernel_launch: ws_size=%zu < needed %zu\n", ws_size, WS_NEED);
    return;
  }
  char* ws = (char*)d_ws;
  unsigned short* xb  = (unsigned short*)(ws + OFF_XB);
  unsigned short* wqb = (unsigned short*)(ws + OFF_WQ);   // wq,wk,wv,wo contiguous
  unsigned short* wvb = wqb + 2 * 1048576;
  unsigned short* wob = (unsigned short*)(ws + OFF_WO);
  unsigned short* Qb  = (unsigned short*)(ws + OFF_Q);
  unsigned short* Vt  = (unsigned short*)(ws + OFF_VT);
  float*          rs  = (float*)(ws + OFF_RS);
  unsigned short* Pb  = (unsigned short*)(ws + OFF_P);
  unsigned short* Cx  = (unsigned short*)(ws + OFF_CTX);

  // 1) convert x + all 4 weights to bf16 (one launch)
  cvt_all<<<12288, 256, 0, stream>>>(x, wq, wk, wv, wo, xb, wqb);

  // 2) fused Q,K: z selects weight (bStride) and output (cStride); 1024 blocks
  gemmP<unsigned short, 0><<<dim3(8, 64, 2), 256, 0, stream>>>(
      xb, wqb, Qb, 1024, 1024, 1024, 16, 0, 1048576LL, 8388608LL, 1.0f,
      nullptr, 0);

  // 3) V^T directly: Vt[e][s] = sum_d Wv[e,d] x[s,d]; M=1024, N=8192; 512 blocks
  gemmP<unsigned short, 0><<<dim3(64, 8, 1), 256, 0, stream>>>(
      wvb, xb, Vt, 1024, 1024, 8192, 16, 0, 0, 0, 1.0f, nullptr, 0);

  // 4) expS = exp(Q @ K^T / 32) -> bf16 (per batch, M=N=2048, K=1024); 1024 blocks
  gemmP<unsigned short, 1><<<dim3(16, 16, 4), 256, 0, stream>>>(
      Qb, Qb + 8388608, Pb, 1024, 1024, 2048, 16,
      2097152LL, 2097152LL, 4194304LL, 0.03125f, nullptr, 0);

  // 5) rowsumInv (wave per row); 2048 blocks
  rowsum_inv<<<2048, 256, 0, stream>>>(Pb, rs);

  // 6) ctx = (expS @ V) * rsInv  (per batch, M=2048, N=1024, K=2048); 512 blocks
  gemmP<unsigned short, 2><<<dim3(8, 16, 4), 256, 0, stream>>>(
      Pb, Vt, Cx, 2048, 8192, 1024, 32,
      4194304LL, 2048LL, 2097152LL, 1.0f, rs, 2048LL);

  // 7) out = ctx @ wo^T  (M=8192, N=1024, K=1024); 512 blocks
  gemmP<float, 0><<<dim3(8, 64, 1), 256, 0, stream>>>(
      Cx, wob, out, 1024, 1024, 1024, 16, 0, 0, 0, 1.0f, nullptr, 0);
}